// Round 20
// baseline (212.615 us; speedup 1.0000x reference)
//
#include <hip/hip_runtime.h>

// GAE: h1 = relu(spmm(X@W1)); h2 = relu(spmm(h1@W2)); Z = spmm(h2@W3);
// A = sigmoid(Z @ Z^T).  Outputs: [A (12288x12288), Z (12288x16)] fp32, concat.
//
// 7 dispatches: memset(cnt+t1) -> ELL-scatter -> gemm1-MFMA -> spmm+relu+@W2
//   -> spmm+relu+@W3 -> spmm16(+bf16) -> decode_mfma.
// R20: scatter UNFUSED from gemm1 (scatter blocks no longer inherit gemm1's
// VGPR/LDS allocation -> full occupancy for the latency-bound scatter).
// gemm1 interior = R17 (best, 203us).

constexpr int NN = 12288;   // nodes
constexpr int NE = 393216;  // edges
constexpr int KD = 1433;    // input dim
constexpr int CAP = 96;     // ELL row capacity (Poisson(32): P(deg>96) ~ 1e-18)

typedef float f32x4 __attribute__((ext_vector_type(4)));
typedef float f32x4u __attribute__((ext_vector_type(4), aligned(4)));  // 4B-aligned vec load
typedef float f32x16 __attribute__((ext_vector_type(16)));
typedef short shortx8 __attribute__((ext_vector_type(8)));

__device__ __forceinline__ unsigned short f2bf(float v) {
    unsigned int b = __float_as_uint(v);
    return (unsigned short)((b + 0x7FFFu + ((b >> 16) & 1u)) >> 16);
}

// ---------------- ELL scatter (own dispatch: ~16 VGPR, 0 LDS, full occupancy) ----------------
__global__ __launch_bounds__(256) void ell_scatter(const int* __restrict__ er,
                                                   const int* __restrict__ ec,
                                                   const float* __restrict__ ev,
                                                   int* __restrict__ cnt,
                                                   uint2* __restrict__ ebuf) {
    int e = blockIdx.x * 256 + threadIdx.x;
    int r = er[e];
    int p = atomicAdd(&cnt[r], 1);
    if (p < CAP) ebuf[(size_t)r * CAP + p] = make_uint2((unsigned)ec[e], __float_as_uint(ev[e]));
}

// ---------------- gemm1: X@W1 via MFMA (bf16), R17 interior ----------------
constexpr int KC = 256;              // k-chunk
constexpr int NCH = 6;               // 256x5 + 153
constexpr int XST = KC + 8;          // W^T LDS stride (bf16)
constexpr int G1B = (NN / 64) * NCH; // 192 row-blocks x 6 chunks = 1152

__global__ __launch_bounds__(256) void gemm1_mfma(const float* __restrict__ X,
                                                  const float* __restrict__ W,
                                                  float* __restrict__ out) {
    __shared__ unsigned short wt[32 * XST];  // W1^T, bf16 [col][k], zero-padded

    int rgB   = blockIdx.x / NCH;        // row block (64 rows)
    int chunk = blockIdx.x % NCH;
    int r0 = rgB * 64;
    int k0 = chunk * KC;
    int kt = min(KC, KD - k0);           // 256 or 153
    int nm = (kt + 15) >> 4;             // 16 or 10
    int t = threadIdx.x;

    // stage W1^T (zero-padded -> zero B kills OOB-k A garbage)
    int wtot = nm * 16 * 32;
    for (int e = t; e < wtot; e += 256) {
        int k = e >> 5, c = e & 31;
        float v = (k < kt) ? W[(size_t)(k0 + k) * 32 + c] : 0.f;
        wt[c * XST + k] = f2bf(v);
    }
    __syncthreads();

    int w = t >> 6, l = t & 63;
    int rg = w >> 1;                     // 32-row group
    int lr = l & 31, lh = l >> 5;
    int row = r0 + rg * 32 + lr;
    const float* xr = X + (size_t)row * KD + k0 + lh * 8;
    const unsigned short* wbase = wt + lr * XST + lh * 8;
    f32x16 acc = {0.f};
    for (int m = (w & 1); m < nm; m += 2) {
        int kk = m * 16 + lh * 8;        // fragment k start (rel. to k0)
        float xv[8];
        if (kk + 8 <= kt) {
            f32x4u v0 = *(const f32x4u*)(xr + m * 16);
            f32x4u v1 = *(const f32x4u*)(xr + m * 16 + 4);
#pragma unroll
            for (int j = 0; j < 4; ++j) { xv[j] = v0[j]; xv[4 + j] = v1[j]; }
        } else {
#pragma unroll
            for (int j = 0; j < 8; ++j) xv[j] = (kk + j < kt) ? xr[m * 16 + j] : 0.f;
        }
        shortx8 a;
#pragma unroll
        for (int j = 0; j < 8; ++j) a[j] = (short)f2bf(xv[j]);
        shortx8 b = *(const shortx8*)(wbase + m * 16);
        acc = __builtin_amdgcn_mfma_f32_32x32x16_bf16(a, b, acc, 0, 0, 0);
    }
    // D: col=lr, row=(q&3)+8*(q>>2)+4*lh (m74-verified)
#pragma unroll
    for (int q = 0; q < 16; ++q) {
        int rf = (q & 3) + 8 * (q >> 2) + 4 * lh;
        atomicAdd(&out[(size_t)(r0 + rg * 32 + rf) * 32 + lr], acc[q]);
    }
}

// ---------------- SpMM(ELL) + relu + dense GEMM, edge-split ----------------
template <int CO>
__global__ __launch_bounds__(256) void spmm_gemm(const float* __restrict__ in,
                                                 const float* __restrict__ Wm,
                                                 float* __restrict__ out,
                                                 const int* __restrict__ cnt,
                                                 const uint2* __restrict__ ebuf) {
    int tid = blockIdx.x * 256 + threadIdx.x;
    int r = tid >> 6;               // one wave per row
    int lane = threadIdx.x & 63;
    int c = lane & 31, half = lane >> 5;
    int co = c & (CO - 1);
    float wcol[32];
#pragma unroll
    for (int k = 0; k < 32; ++k) wcol[k] = Wm[k * CO + co];
    int deg = min(cnt[r], CAP);
    int mid = (deg >> 1) & ~1;      // even split point (eb4-aligned)
    int lo = half ? mid : 0;
    int hi = half ? deg : mid;
    const uint2* eb2 = ebuf + (size_t)r * CAP;
    const uint4* eb4 = (const uint4*)eb2;
    float acc = 0.f;
    int i = lo;
#pragma unroll 2
    for (; i + 4 <= hi; i += 4) {
        uint4 e01 = eb4[i >> 1], e23 = eb4[(i >> 1) + 1];
        acc += __uint_as_float(e01.y) * in[(size_t)e01.x * 32 + c];
        acc += __uint_as_float(e01.w) * in[(size_t)e01.z * 32 + c];
        acc += __uint_as_float(e23.y) * in[(size_t)e23.x * 32 + c];
        acc += __uint_as_float(e23.w) * in[(size_t)e23.z * 32 + c];
    }
    for (; i < hi; ++i) {
        uint2 e = eb2[i];
        acc += __uint_as_float(e.y) * in[(size_t)e.x * 32 + c];
    }
    float h = fmaxf(acc + __shfl_xor(acc, 32), 0.f);
    float o = 0.f;
#pragma unroll
    for (int k = 0; k < 32; ++k)
        o += __shfl(h, (lane & 32) + k) * wcol[k];
    if (half == 0 && c < CO) out[(size_t)r * CO + co] = o;
}

// ---------------- SpMM(ELL) width 16, edge-split -> Z (fp32) + Zb (bf16) ----------------
__global__ __launch_bounds__(256) void spmm16(const float* __restrict__ in,
                                              float* __restrict__ out,
                                              unsigned short* __restrict__ zb,
                                              const int* __restrict__ cnt,
                                              const uint2* __restrict__ ebuf) {
    int tid = blockIdx.x * 256 + threadIdx.x;
    int r = tid >> 5;
    int sub = tid & 31;
    int c = sub & 15, half = sub >> 4;
    int deg = min(cnt[r], CAP);
    int mid = (deg >> 1) & ~1;
    int lo = half ? mid : 0;
    int hi = half ? deg : mid;
    const uint2* eb2 = ebuf + (size_t)r * CAP;
    const uint4* eb4 = (const uint4*)eb2;
    float acc = 0.f;
    int i = lo;
#pragma unroll 2
    for (; i + 4 <= hi; i += 4) {
        uint4 e01 = eb4[i >> 1], e23 = eb4[(i >> 1) + 1];
        acc += __uint_as_float(e01.y) * in[(size_t)e01.x * 16 + c];
        acc += __uint_as_float(e01.w) * in[(size_t)e01.z * 16 + c];
        acc += __uint_as_float(e23.y) * in[(size_t)e23.x * 16 + c];
        acc += __uint_as_float(e23.w) * in[(size_t)e23.z * 16 + c];
    }
    for (; i < hi; ++i) {
        uint2 e = eb2[i];
        acc += __uint_as_float(e.y) * in[(size_t)e.x * 16 + c];
    }
    float sv = acc + __shfl_xor(acc, 16);
    if (half == 0) {
        out[(size_t)r * 16 + c] = sv;
        zb[(size_t)r * 16 + c] = f2bf(sv);
    }
}

// ---------------- decode via MFMA: A = sigmoid(Zb @ Zb^T) ----------------
// 64(i) x 256(j) tile / 4 waves side-by-side; wave = 64x64 = 4 MFMA.
// NT scalar stores; bj-fastest XCD swizzle.
__global__ __launch_bounds__(256) void decode_mfma(const unsigned short* __restrict__ Zb,
                                                   float* __restrict__ A) {
    int id = blockIdx.x;
    int f = (id & 7) * (9216 / 8) + (id >> 3);   // XCD swizzle (bijective: 9216%8==0)
    int bi = f / 48, bj = f % 48;                // 192 x 48 tiles of 64x256
    int w = threadIdx.x >> 6;
    int l = threadIdx.x & 63;
    int R = bi * 64;
    int C = bj * 256 + w * 64;
    int lr = l & 31, lh = l >> 5;

    shortx8 a0 = *(const shortx8*)(Zb + ((size_t)(R + lr) << 4) + lh * 8);
    shortx8 a1 = *(const shortx8*)(Zb + ((size_t)(R + 32 + lr) << 4) + lh * 8);
    shortx8 b0 = *(const shortx8*)(Zb + ((size_t)(C + lr) << 4) + lh * 8);
    shortx8 b1 = *(const shortx8*)(Zb + ((size_t)(C + 32 + lr) << 4) + lh * 8);

    f32x16 acc00 = {0.f}, acc01 = {0.f}, acc10 = {0.f}, acc11 = {0.f};
    acc00 = __builtin_amdgcn_mfma_f32_32x32x16_bf16(a0, b0, acc00, 0, 0, 0);
    acc01 = __builtin_amdgcn_mfma_f32_32x32x16_bf16(a0, b1, acc01, 0, 0, 0);
    acc10 = __builtin_amdgcn_mfma_f32_32x32x16_bf16(a1, b0, acc10, 0, 0, 0);
    acc11 = __builtin_amdgcn_mfma_f32_32x32x16_bf16(a1, b1, acc11, 0, 0, 0);

#pragma unroll
    for (int q = 0; q < 16; ++q) {
        int rf = (q & 3) + 8 * (q >> 2) + 4 * lh;
        float s00 = __fdividef(1.0f, 1.0f + __expf(-acc00[q]));
        float s01 = __fdividef(1.0f, 1.0f + __expf(-acc01[q]));
        float s10 = __fdividef(1.0f, 1.0f + __expf(-acc10[q]));
        float s11 = __fdividef(1.0f, 1.0f + __expf(-acc11[q]));
        __builtin_nontemporal_store(s00, &A[(size_t)(R + rf) * NN + C + lr]);
        __builtin_nontemporal_store(s01, &A[(size_t)(R + rf) * NN + C + 32 + lr]);
        __builtin_nontemporal_store(s10, &A[(size_t)(R + 32 + rf) * NN + C + lr]);
        __builtin_nontemporal_store(s11, &A[(size_t)(R + 32 + rf) * NN + C + 32 + lr]);
    }
}

extern "C" void kernel_launch(void* const* d_in, const int* in_sizes, int n_in,
                              void* d_out, int out_size, void* d_ws, size_t ws_size,
                              hipStream_t stream) {
    const float* X  = (const float*)d_in[0];
    const float* W1 = (const float*)d_in[1];
    const float* W2 = (const float*)d_in[2];
    const float* W3 = (const float*)d_in[3];
    const float* ev = (const float*)d_in[4];
    const int*   er = (const int*)d_in[5];
    const int*   ec = (const int*)d_in[6];

    float* A = (float*)d_out;                 // [NN, NN]
    float* Z = A + (size_t)NN * NN;           // [NN, 16]

    // ws layout: [cnt][t1][t2][t3] — cnt+t1 zeroed by ONE memset.
    int*   cnt = (int*)d_ws;                  // [NN]
    float* t1 = (float*)(cnt + NN);           // [NN, 32]  X@W1 (atomic-accum)
    float* t2 = t1 + (size_t)NN * 32;         // [NN, 32]
    float* t3 = t2 + (size_t)NN * 32;         // [NN, 16]
    unsigned short* Zb = (unsigned short*)t1; // [NN, 16] bf16 (t1 dead by then)

    // ELL edge buffer in the tail of A (decode overwrites it last).
    uint2* ebuf = (uint2*)(A + (size_t)140000000);

    (void)hipMemsetAsync(cnt, 0, NN * sizeof(int) + (size_t)NN * 32 * sizeof(float), stream);

    // scatter (own dispatch, full occupancy) then gemm1
    ell_scatter<<<NE / 256, 256, 0, stream>>>(er, ec, ev, cnt, ebuf);
    gemm1_mfma<<<G1B, 256, 0, stream>>>(X, W1, t1);

    // t2 = relu(spmm(t1)) @ W2   (one wave per row)
    spmm_gemm<32><<<NN * 64 / 256, 256, 0, stream>>>(t1, W2, t2, cnt, ebuf);
    // t3 = relu(spmm(t2)) @ W3
    spmm_gemm<16><<<NN * 64 / 256, 256, 0, stream>>>(t2, W3, t3, cnt, ebuf);
    // Z = spmm(t3); Zb = bf16(Z)   (32 lanes per row)
    spmm16<<<NN * 32 / 256, 256, 0, stream>>>(t3, Z, Zb, cnt, ebuf);

    // A = sigmoid(Z @ Z^T) via MFMA
    decode_mfma<<<192 * 48, 256, 0, stream>>>(Zb, A);
}

// Round 21
// 205.898 us; speedup vs baseline: 1.0326x; 1.0326x over previous
//
#include <hip/hip_runtime.h>

// GAE: h1 = relu(spmm(X@W1)); h2 = relu(spmm(h1@W2)); Z = spmm(h2@W3);
// A = sigmoid(Z @ Z^T).  Outputs: [A (12288x12288), Z (12288x16)] fp32, concat.
//
// 5 dispatches: memset(cnt+t1) -> [gemm1-MFMA || ELL-scatter] -> spmm+relu+@W2
//   -> spmm32 (pure gather) -> spmm+relu+@W3-commuted (+Z,Zb) -> decode_mfma.
// R21: W3 commuted out of the final spmm (both linear):
//   Z = spmm(relu(b)@W3-per-row) == (spmm o relu)(b) @ W3, b = spmm(t2).
// Chain shrinks 3 kernels -> 2. Front-end and decode = R17 (best, 203us).

constexpr int NN = 12288;   // nodes
constexpr int NE = 393216;  // edges
constexpr int KD = 1433;    // input dim
constexpr int CAP = 96;     // ELL row capacity (Poisson(32): P(deg>96) ~ 1e-18)

typedef float f32x4 __attribute__((ext_vector_type(4)));
typedef float f32x4u __attribute__((ext_vector_type(4), aligned(4)));  // 4B-aligned vec load
typedef float f32x16 __attribute__((ext_vector_type(16)));
typedef short shortx8 __attribute__((ext_vector_type(8)));

__device__ __forceinline__ unsigned short f2bf(float v) {
    unsigned int b = __float_as_uint(v);
    return (unsigned short)((b + 0x7FFFu + ((b >> 16) & 1u)) >> 16);
}

// ---------------- fused: gemm1 (X@W1 via MFMA, bf16) || ELL scatter ----------------
constexpr int KC = 256;              // k-chunk
constexpr int NCH = 6;               // 256x5 + 153
constexpr int XST = KC + 8;          // W^T LDS stride (bf16)
constexpr int G1B = (NN / 64) * NCH; // 192 row-blocks x 6 chunks = 1152

__global__ __launch_bounds__(256) void k_scatter_gemm1(const int* __restrict__ er,
                                                       const int* __restrict__ ec,
                                                       const float* __restrict__ ev,
                                                       int* __restrict__ cnt,
                                                       uint2* __restrict__ ebuf,
                                                       const float* __restrict__ X,
                                                       const float* __restrict__ W,
                                                       float* __restrict__ out) {
    if (blockIdx.x >= G1B) {
        int e = (blockIdx.x - G1B) * 256 + threadIdx.x;
        int r = er[e];
        int p = atomicAdd(&cnt[r], 1);
        if (p < CAP) ebuf[(size_t)r * CAP + p] = make_uint2((unsigned)ec[e], __float_as_uint(ev[e]));
        return;
    }
    __shared__ unsigned short wt[32 * XST];  // W1^T, bf16 [col][k], zero-padded

    int rgB   = blockIdx.x / NCH;        // row block (64 rows)
    int chunk = blockIdx.x % NCH;
    int r0 = rgB * 64;
    int k0 = chunk * KC;
    int kt = min(KC, KD - k0);           // 256 or 153
    int nm = (kt + 15) >> 4;             // 16 or 10
    int t = threadIdx.x;

    // stage W1^T (zero-padded -> zero B kills OOB-k A garbage)
    int wtot = nm * 16 * 32;
    for (int e = t; e < wtot; e += 256) {
        int k = e >> 5, c = e & 31;
        float v = (k < kt) ? W[(size_t)(k0 + k) * 32 + c] : 0.f;
        wt[c * XST + k] = f2bf(v);
    }
    __syncthreads();

    int w = t >> 6, l = t & 63;
    int rg = w >> 1;                     // 32-row group
    int lr = l & 31, lh = l >> 5;
    int row = r0 + rg * 32 + lr;
    const float* xr = X + (size_t)row * KD + k0 + lh * 8;
    const unsigned short* wbase = wt + lr * XST + lh * 8;
    f32x16 acc = {0.f};
    for (int m = (w & 1); m < nm; m += 2) {
        int kk = m * 16 + lh * 8;        // fragment k start (rel. to k0)
        float xv[8];
        if (kk + 8 <= kt) {
            f32x4u v0 = *(const f32x4u*)(xr + m * 16);
            f32x4u v1 = *(const f32x4u*)(xr + m * 16 + 4);
#pragma unroll
            for (int j = 0; j < 4; ++j) { xv[j] = v0[j]; xv[4 + j] = v1[j]; }
        } else {
#pragma unroll
            for (int j = 0; j < 8; ++j) xv[j] = (kk + j < kt) ? xr[m * 16 + j] : 0.f;
        }
        shortx8 a;
#pragma unroll
        for (int j = 0; j < 8; ++j) a[j] = (short)f2bf(xv[j]);
        shortx8 b = *(const shortx8*)(wbase + m * 16);
        acc = __builtin_amdgcn_mfma_f32_32x32x16_bf16(a, b, acc, 0, 0, 0);
    }
    // D: col=lr, row=(q&3)+8*(q>>2)+4*lh (m74-verified)
#pragma unroll
    for (int q = 0; q < 16; ++q) {
        int rf = (q & 3) + 8 * (q >> 2) + 4 * lh;
        atomicAdd(&out[(size_t)(r0 + rg * 32 + rf) * 32 + lr], acc[q]);
    }
}

// ---------------- layer1: SpMM(ELL) + relu + @W2, edge-split ----------------
__global__ __launch_bounds__(256) void spmm_gemm32(const float* __restrict__ in,
                                                   const float* __restrict__ Wm,
                                                   float* __restrict__ out,
                                                   const int* __restrict__ cnt,
                                                   const uint2* __restrict__ ebuf) {
    int tid = blockIdx.x * 256 + threadIdx.x;
    int r = tid >> 6;               // one wave per row
    int lane = threadIdx.x & 63;
    int c = lane & 31, half = lane >> 5;
    float wcol[32];
#pragma unroll
    for (int k = 0; k < 32; ++k) wcol[k] = Wm[k * 32 + c];
    int deg = min(cnt[r], CAP);
    int mid = (deg >> 1) & ~1;      // even split point (eb4-aligned)
    int lo = half ? mid : 0;
    int hi = half ? deg : mid;
    const uint2* eb2 = ebuf + (size_t)r * CAP;
    const uint4* eb4 = (const uint4*)eb2;
    float acc = 0.f;
    int i = lo;
#pragma unroll 2
    for (; i + 4 <= hi; i += 4) {
        uint4 e01 = eb4[i >> 1], e23 = eb4[(i >> 1) + 1];
        acc += __uint_as_float(e01.y) * in[(size_t)e01.x * 32 + c];
        acc += __uint_as_float(e01.w) * in[(size_t)e01.z * 32 + c];
        acc += __uint_as_float(e23.y) * in[(size_t)e23.x * 32 + c];
        acc += __uint_as_float(e23.w) * in[(size_t)e23.z * 32 + c];
    }
    for (; i < hi; ++i) {
        uint2 e = eb2[i];
        acc += __uint_as_float(e.y) * in[(size_t)e.x * 32 + c];
    }
    float h = fmaxf(acc + __shfl_xor(acc, 32), 0.f);
    float o = 0.f;
#pragma unroll
    for (int k = 0; k < 32; ++k)
        o += __shfl(h, (lane & 32) + k) * wcol[k];
    if (half == 0) out[(size_t)r * 32 + c] = o;
}

// ---------------- layer2: pure SpMM(ELL) width 32 (b = spmm(t2)), edge-split ----------------
__global__ __launch_bounds__(256) void spmm32(const float* __restrict__ in,
                                              float* __restrict__ out,
                                              const int* __restrict__ cnt,
                                              const uint2* __restrict__ ebuf) {
    int tid = blockIdx.x * 256 + threadIdx.x;
    int r = tid >> 6;
    int lane = threadIdx.x & 63;
    int c = lane & 31, half = lane >> 5;
    int deg = min(cnt[r], CAP);
    int mid = (deg >> 1) & ~1;
    int lo = half ? mid : 0;
    int hi = half ? deg : mid;
    const uint2* eb2 = ebuf + (size_t)r * CAP;
    const uint4* eb4 = (const uint4*)eb2;
    float acc = 0.f;
    int i = lo;
#pragma unroll 2
    for (; i + 4 <= hi; i += 4) {
        uint4 e01 = eb4[i >> 1], e23 = eb4[(i >> 1) + 1];
        acc += __uint_as_float(e01.y) * in[(size_t)e01.x * 32 + c];
        acc += __uint_as_float(e01.w) * in[(size_t)e01.z * 32 + c];
        acc += __uint_as_float(e23.y) * in[(size_t)e23.x * 32 + c];
        acc += __uint_as_float(e23.w) * in[(size_t)e23.z * 32 + c];
    }
    for (; i < hi; ++i) {
        uint2 e = eb2[i];
        acc += __uint_as_float(e.y) * in[(size_t)e.x * 32 + c];
    }
    float s = acc + __shfl_xor(acc, 32);
    if (half == 0) out[(size_t)r * 32 + c] = s;   // pre-relu (relu applied by reader)
}

// ---------------- layer3: Z = (spmm o relu)(b) @ W3  (W3 commuted), edge-split ----------------
__global__ __launch_bounds__(256) void spmm_w3(const float* __restrict__ in,
                                               const float* __restrict__ Wm,
                                               float* __restrict__ Z,
                                               unsigned short* __restrict__ zb,
                                               const int* __restrict__ cnt,
                                               const uint2* __restrict__ ebuf) {
    int tid = blockIdx.x * 256 + threadIdx.x;
    int r = tid >> 6;
    int lane = threadIdx.x & 63;
    int c = lane & 31, half = lane >> 5;
    int co = c & 15;
    float wcol[32];
#pragma unroll
    for (int k = 0; k < 32; ++k) wcol[k] = Wm[k * 16 + co];
    int deg = min(cnt[r], CAP);
    int mid = (deg >> 1) & ~1;
    int lo = half ? mid : 0;
    int hi = half ? deg : mid;
    const uint2* eb2 = ebuf + (size_t)r * CAP;
    const uint4* eb4 = (const uint4*)eb2;
    float acc = 0.f;
    int i = lo;
#pragma unroll 2
    for (; i + 4 <= hi; i += 4) {
        uint4 e01 = eb4[i >> 1], e23 = eb4[(i >> 1) + 1];
        acc += __uint_as_float(e01.y) * fmaxf(in[(size_t)e01.x * 32 + c], 0.f);
        acc += __uint_as_float(e01.w) * fmaxf(in[(size_t)e01.z * 32 + c], 0.f);
        acc += __uint_as_float(e23.y) * fmaxf(in[(size_t)e23.x * 32 + c], 0.f);
        acc += __uint_as_float(e23.w) * fmaxf(in[(size_t)e23.z * 32 + c], 0.f);
    }
    for (; i < hi; ++i) {
        uint2 e = eb2[i];
        acc += __uint_as_float(e.y) * fmaxf(in[(size_t)e.x * 32 + c], 0.f);
    }
    float g = acc + __shfl_xor(acc, 32);   // g[r,c] = spmm(relu(b))[r,c], full row in half-wave
    float o = 0.f;
#pragma unroll
    for (int k = 0; k < 32; ++k)
        o += __shfl(g, (lane & 32) + k) * wcol[k];
    if (half == 0 && c < 16) {
        Z[(size_t)r * 16 + co] = o;
        zb[(size_t)r * 16 + co] = f2bf(o);
    }
}

// ---------------- decode via MFMA: A = sigmoid(Zb @ Zb^T) ----------------
// 64(i) x 256(j) tile / 4 waves side-by-side; wave = 64x64 = 4 MFMA.
// NT scalar stores; bj-fastest XCD swizzle.
__global__ __launch_bounds__(256) void decode_mfma(const unsigned short* __restrict__ Zb,
                                                   float* __restrict__ A) {
    int id = blockIdx.x;
    int f = (id & 7) * (9216 / 8) + (id >> 3);   // XCD swizzle (bijective: 9216%8==0)
    int bi = f / 48, bj = f % 48;                // 192 x 48 tiles of 64x256
    int w = threadIdx.x >> 6;
    int l = threadIdx.x & 63;
    int R = bi * 64;
    int C = bj * 256 + w * 64;
    int lr = l & 31, lh = l >> 5;

    shortx8 a0 = *(const shortx8*)(Zb + ((size_t)(R + lr) << 4) + lh * 8);
    shortx8 a1 = *(const shortx8*)(Zb + ((size_t)(R + 32 + lr) << 4) + lh * 8);
    shortx8 b0 = *(const shortx8*)(Zb + ((size_t)(C + lr) << 4) + lh * 8);
    shortx8 b1 = *(const shortx8*)(Zb + ((size_t)(C + 32 + lr) << 4) + lh * 8);

    f32x16 acc00 = {0.f}, acc01 = {0.f}, acc10 = {0.f}, acc11 = {0.f};
    acc00 = __builtin_amdgcn_mfma_f32_32x32x16_bf16(a0, b0, acc00, 0, 0, 0);
    acc01 = __builtin_amdgcn_mfma_f32_32x32x16_bf16(a0, b1, acc01, 0, 0, 0);
    acc10 = __builtin_amdgcn_mfma_f32_32x32x16_bf16(a1, b0, acc10, 0, 0, 0);
    acc11 = __builtin_amdgcn_mfma_f32_32x32x16_bf16(a1, b1, acc11, 0, 0, 0);

#pragma unroll
    for (int q = 0; q < 16; ++q) {
        int rf = (q & 3) + 8 * (q >> 2) + 4 * lh;
        float s00 = __fdividef(1.0f, 1.0f + __expf(-acc00[q]));
        float s01 = __fdividef(1.0f, 1.0f + __expf(-acc01[q]));
        float s10 = __fdividef(1.0f, 1.0f + __expf(-acc10[q]));
        float s11 = __fdividef(1.0f, 1.0f + __expf(-acc11[q]));
        __builtin_nontemporal_store(s00, &A[(size_t)(R + rf) * NN + C + lr]);
        __builtin_nontemporal_store(s01, &A[(size_t)(R + rf) * NN + C + 32 + lr]);
        __builtin_nontemporal_store(s10, &A[(size_t)(R + 32 + rf) * NN + C + lr]);
        __builtin_nontemporal_store(s11, &A[(size_t)(R + 32 + rf) * NN + C + 32 + lr]);
    }
}

extern "C" void kernel_launch(void* const* d_in, const int* in_sizes, int n_in,
                              void* d_out, int out_size, void* d_ws, size_t ws_size,
                              hipStream_t stream) {
    const float* X  = (const float*)d_in[0];
    const float* W1 = (const float*)d_in[1];
    const float* W2 = (const float*)d_in[2];
    const float* W3 = (const float*)d_in[3];
    const float* ev = (const float*)d_in[4];
    const int*   er = (const int*)d_in[5];
    const int*   ec = (const int*)d_in[6];

    float* A = (float*)d_out;                 // [NN, NN]
    float* Z = A + (size_t)NN * NN;           // [NN, 16]

    // ws layout: [cnt][t1][t2][t3] — cnt+t1 zeroed by ONE memset.
    int*   cnt = (int*)d_ws;                  // [NN]
    float* t1 = (float*)(cnt + NN);           // [NN, 32]  X@W1 (atomic-accum)
    float* t2 = t1 + (size_t)NN * 32;         // [NN, 32]  h1@W2
    float* t3 = t2 + (size_t)NN * 32;         // [NN, 32]  b = spmm(t2)
    unsigned short* Zb = (unsigned short*)t1; // [NN, 16] bf16 (t1 dead by then)

    // ELL edge buffer in the tail of A (decode overwrites it last).
    uint2* ebuf = (uint2*)(A + (size_t)140000000);

    (void)hipMemsetAsync(cnt, 0, NN * sizeof(int) + (size_t)NN * 32 * sizeof(float), stream);

    // gemm1-MFMA (blocks 0..1151) || ELL scatter (blocks 1152..2687)
    k_scatter_gemm1<<<G1B + NE / 256, 256, 0, stream>>>(er, ec, ev, cnt, ebuf, X, W1, t1);

    // t2 = relu(spmm(t1)) @ W2   (one wave per row)
    spmm_gemm32<<<NN * 64 / 256, 256, 0, stream>>>(t1, W2, t2, cnt, ebuf);
    // t3 = b = spmm(t2)          (pure gather)
    spmm32<<<NN * 64 / 256, 256, 0, stream>>>(t2, t3, cnt, ebuf);
    // Z = spmm(relu(b)) @ W3  (+Zb)  — W3 commuted out of the spmm
    spmm_w3<<<NN * 64 / 256, 256, 0, stream>>>(t3, W3, Z, Zb, cnt, ebuf);

    // A = sigmoid(Z @ Z^T) via MFMA
    decode_mfma<<<192 * 48, 256, 0, stream>>>(Zb, A);
}

// Round 22
// 199.260 us; speedup vs baseline: 1.0670x; 1.0333x over previous
//
#include <hip/hip_runtime.h>

// GAE: h1 = relu(spmm(X@W1)); h2 = relu(spmm(h1@W2)); Z = spmm(h2@W3);
// A = sigmoid(Z @ Z^T).  Outputs: [A (12288x12288), Z (12288x16)] fp32, concat.
//
// 6 dispatches: memset(cnt+t1) -> [gemm1-MFMA || ELL-scatter] -> spmm+relu+@W2
//   -> spmm32 -> spmm+relu+@W3-commuted (+Z,Zb) -> decode_mfma.
// R22 decode: LDS-staged store epilogue. Sigmoid results staged in a
// [64][260] LDS tile, then flushed as 1KB-contiguous single-row NT dwordx4
// bursts (vs 4 fragmented 256B/row scalar NT streams per wave) -> better
// MC row-buffer locality for the 604MB A write.

constexpr int NN = 12288;   // nodes
constexpr int NE = 393216;  // edges
constexpr int KD = 1433;    // input dim
constexpr int CAP = 96;     // ELL row capacity (Poisson(32): P(deg>96) ~ 1e-18)

typedef float f32x4 __attribute__((ext_vector_type(4)));
typedef float f32x4u __attribute__((ext_vector_type(4), aligned(4)));  // 4B-aligned vec load
typedef float f32x16 __attribute__((ext_vector_type(16)));
typedef short shortx8 __attribute__((ext_vector_type(8)));

__device__ __forceinline__ unsigned short f2bf(float v) {
    unsigned int b = __float_as_uint(v);
    return (unsigned short)((b + 0x7FFFu + ((b >> 16) & 1u)) >> 16);
}

// ---------------- fused: gemm1 (X@W1 via MFMA, bf16) || ELL scatter ----------------
constexpr int KC = 256;              // k-chunk
constexpr int NCH = 6;               // 256x5 + 153
constexpr int XST = KC + 8;          // W^T LDS stride (bf16)
constexpr int G1B = (NN / 64) * NCH; // 192 row-blocks x 6 chunks = 1152

__global__ __launch_bounds__(256) void k_scatter_gemm1(const int* __restrict__ er,
                                                       const int* __restrict__ ec,
                                                       const float* __restrict__ ev,
                                                       int* __restrict__ cnt,
                                                       uint2* __restrict__ ebuf,
                                                       const float* __restrict__ X,
                                                       const float* __restrict__ W,
                                                       float* __restrict__ out) {
    if (blockIdx.x >= G1B) {
        int e = (blockIdx.x - G1B) * 256 + threadIdx.x;
        int r = er[e];
        int p = atomicAdd(&cnt[r], 1);
        if (p < CAP) ebuf[(size_t)r * CAP + p] = make_uint2((unsigned)ec[e], __float_as_uint(ev[e]));
        return;
    }
    __shared__ unsigned short wt[32 * XST];  // W1^T, bf16 [col][k], zero-padded

    int rgB   = blockIdx.x / NCH;        // row block (64 rows)
    int chunk = blockIdx.x % NCH;
    int r0 = rgB * 64;
    int k0 = chunk * KC;
    int kt = min(KC, KD - k0);           // 256 or 153
    int nm = (kt + 15) >> 4;             // 16 or 10
    int t = threadIdx.x;

    // stage W1^T (zero-padded -> zero B kills OOB-k A garbage)
    int wtot = nm * 16 * 32;
    for (int e = t; e < wtot; e += 256) {
        int k = e >> 5, c = e & 31;
        float v = (k < kt) ? W[(size_t)(k0 + k) * 32 + c] : 0.f;
        wt[c * XST + k] = f2bf(v);
    }
    __syncthreads();

    int w = t >> 6, l = t & 63;
    int rg = w >> 1;                     // 32-row group
    int lr = l & 31, lh = l >> 5;
    int row = r0 + rg * 32 + lr;
    const float* xr = X + (size_t)row * KD + k0 + lh * 8;
    const unsigned short* wbase = wt + lr * XST + lh * 8;
    f32x16 acc = {0.f};
    for (int m = (w & 1); m < nm; m += 2) {
        int kk = m * 16 + lh * 8;        // fragment k start (rel. to k0)
        float xv[8];
        if (kk + 8 <= kt) {
            f32x4u v0 = *(const f32x4u*)(xr + m * 16);
            f32x4u v1 = *(const f32x4u*)(xr + m * 16 + 4);
#pragma unroll
            for (int j = 0; j < 4; ++j) { xv[j] = v0[j]; xv[4 + j] = v1[j]; }
        } else {
#pragma unroll
            for (int j = 0; j < 8; ++j) xv[j] = (kk + j < kt) ? xr[m * 16 + j] : 0.f;
        }
        shortx8 a;
#pragma unroll
        for (int j = 0; j < 8; ++j) a[j] = (short)f2bf(xv[j]);
        shortx8 b = *(const shortx8*)(wbase + m * 16);
        acc = __builtin_amdgcn_mfma_f32_32x32x16_bf16(a, b, acc, 0, 0, 0);
    }
    // D: col=lr, row=(q&3)+8*(q>>2)+4*lh (m74-verified)
#pragma unroll
    for (int q = 0; q < 16; ++q) {
        int rf = (q & 3) + 8 * (q >> 2) + 4 * lh;
        atomicAdd(&out[(size_t)(r0 + rg * 32 + rf) * 32 + lr], acc[q]);
    }
}

// ---------------- layer1: SpMM(ELL) + relu + @W2, edge-split ----------------
__global__ __launch_bounds__(256) void spmm_gemm32(const float* __restrict__ in,
                                                   const float* __restrict__ Wm,
                                                   float* __restrict__ out,
                                                   const int* __restrict__ cnt,
                                                   const uint2* __restrict__ ebuf) {
    int tid = blockIdx.x * 256 + threadIdx.x;
    int r = tid >> 6;               // one wave per row
    int lane = threadIdx.x & 63;
    int c = lane & 31, half = lane >> 5;
    float wcol[32];
#pragma unroll
    for (int k = 0; k < 32; ++k) wcol[k] = Wm[k * 32 + c];
    int deg = min(cnt[r], CAP);
    int mid = (deg >> 1) & ~1;      // even split point (eb4-aligned)
    int lo = half ? mid : 0;
    int hi = half ? deg : mid;
    const uint2* eb2 = ebuf + (size_t)r * CAP;
    const uint4* eb4 = (const uint4*)eb2;
    float acc = 0.f;
    int i = lo;
#pragma unroll 2
    for (; i + 4 <= hi; i += 4) {
        uint4 e01 = eb4[i >> 1], e23 = eb4[(i >> 1) + 1];
        acc += __uint_as_float(e01.y) * in[(size_t)e01.x * 32 + c];
        acc += __uint_as_float(e01.w) * in[(size_t)e01.z * 32 + c];
        acc += __uint_as_float(e23.y) * in[(size_t)e23.x * 32 + c];
        acc += __uint_as_float(e23.w) * in[(size_t)e23.z * 32 + c];
    }
    for (; i < hi; ++i) {
        uint2 e = eb2[i];
        acc += __uint_as_float(e.y) * in[(size_t)e.x * 32 + c];
    }
    float h = fmaxf(acc + __shfl_xor(acc, 32), 0.f);
    float o = 0.f;
#pragma unroll
    for (int k = 0; k < 32; ++k)
        o += __shfl(h, (lane & 32) + k) * wcol[k];
    if (half == 0) out[(size_t)r * 32 + c] = o;
}

// ---------------- layer2: pure SpMM(ELL) width 32, edge-split ----------------
__global__ __launch_bounds__(256) void spmm32(const float* __restrict__ in,
                                              float* __restrict__ out,
                                              const int* __restrict__ cnt,
                                              const uint2* __restrict__ ebuf) {
    int tid = blockIdx.x * 256 + threadIdx.x;
    int r = tid >> 6;
    int lane = threadIdx.x & 63;
    int c = lane & 31, half = lane >> 5;
    int deg = min(cnt[r], CAP);
    int mid = (deg >> 1) & ~1;
    int lo = half ? mid : 0;
    int hi = half ? deg : mid;
    const uint2* eb2 = ebuf + (size_t)r * CAP;
    const uint4* eb4 = (const uint4*)eb2;
    float acc = 0.f;
    int i = lo;
#pragma unroll 2
    for (; i + 4 <= hi; i += 4) {
        uint4 e01 = eb4[i >> 1], e23 = eb4[(i >> 1) + 1];
        acc += __uint_as_float(e01.y) * in[(size_t)e01.x * 32 + c];
        acc += __uint_as_float(e01.w) * in[(size_t)e01.z * 32 + c];
        acc += __uint_as_float(e23.y) * in[(size_t)e23.x * 32 + c];
        acc += __uint_as_float(e23.w) * in[(size_t)e23.z * 32 + c];
    }
    for (; i < hi; ++i) {
        uint2 e = eb2[i];
        acc += __uint_as_float(e.y) * in[(size_t)e.x * 32 + c];
    }
    float s = acc + __shfl_xor(acc, 32);
    if (half == 0) out[(size_t)r * 32 + c] = s;   // pre-relu (relu applied by reader)
}

// ---------------- layer3: Z = (spmm o relu)(b) @ W3  (W3 commuted), edge-split ----------------
__global__ __launch_bounds__(256) void spmm_w3(const float* __restrict__ in,
                                               const float* __restrict__ Wm,
                                               float* __restrict__ Z,
                                               unsigned short* __restrict__ zb,
                                               const int* __restrict__ cnt,
                                               const uint2* __restrict__ ebuf) {
    int tid = blockIdx.x * 256 + threadIdx.x;
    int r = tid >> 6;
    int lane = threadIdx.x & 63;
    int c = lane & 31, half = lane >> 5;
    int co = c & 15;
    float wcol[32];
#pragma unroll
    for (int k = 0; k < 32; ++k) wcol[k] = Wm[k * 16 + co];
    int deg = min(cnt[r], CAP);
    int mid = (deg >> 1) & ~1;
    int lo = half ? mid : 0;
    int hi = half ? deg : mid;
    const uint2* eb2 = ebuf + (size_t)r * CAP;
    const uint4* eb4 = (const uint4*)eb2;
    float acc = 0.f;
    int i = lo;
#pragma unroll 2
    for (; i + 4 <= hi; i += 4) {
        uint4 e01 = eb4[i >> 1], e23 = eb4[(i >> 1) + 1];
        acc += __uint_as_float(e01.y) * fmaxf(in[(size_t)e01.x * 32 + c], 0.f);
        acc += __uint_as_float(e01.w) * fmaxf(in[(size_t)e01.z * 32 + c], 0.f);
        acc += __uint_as_float(e23.y) * fmaxf(in[(size_t)e23.x * 32 + c], 0.f);
        acc += __uint_as_float(e23.w) * fmaxf(in[(size_t)e23.z * 32 + c], 0.f);
    }
    for (; i < hi; ++i) {
        uint2 e = eb2[i];
        acc += __uint_as_float(e.y) * fmaxf(in[(size_t)e.x * 32 + c], 0.f);
    }
    float g = acc + __shfl_xor(acc, 32);   // g[r,c] = spmm(relu(b))[r,c]
    float o = 0.f;
#pragma unroll
    for (int k = 0; k < 32; ++k)
        o += __shfl(g, (lane & 32) + k) * wcol[k];
    if (half == 0 && c < 16) {
        Z[(size_t)r * 16 + co] = o;
        zb[(size_t)r * 16 + co] = f2bf(o);
    }
}

// ---------------- decode via MFMA + LDS-staged row-major flush ----------------
// 64(i) x 256(j) tile / 4 waves; wave = 64x64 = 4 MFMA (unchanged math).
// Epilogue: sigmoid -> LDS [64][260] (2-way bank alias = free), barrier,
// flush 16 iters: each wave-instr = one full row's 1KB as NT dwordx4.
__global__ __launch_bounds__(256) void decode_mfma(const unsigned short* __restrict__ Zb,
                                                   float* __restrict__ A) {
    __shared__ float ts[64][260];
    int id = blockIdx.x;
    int f = (id & 7) * (9216 / 8) + (id >> 3);   // XCD swizzle (bijective: 9216%8==0)
    int bi = f / 48, bj = f % 48;                // 192 x 48 tiles of 64x256
    int w = threadIdx.x >> 6;
    int l = threadIdx.x & 63;
    int R = bi * 64;
    int C = bj * 256 + w * 64;
    int lr = l & 31, lh = l >> 5;

    shortx8 a0 = *(const shortx8*)(Zb + ((size_t)(R + lr) << 4) + lh * 8);
    shortx8 a1 = *(const shortx8*)(Zb + ((size_t)(R + 32 + lr) << 4) + lh * 8);
    shortx8 b0 = *(const shortx8*)(Zb + ((size_t)(C + lr) << 4) + lh * 8);
    shortx8 b1 = *(const shortx8*)(Zb + ((size_t)(C + 32 + lr) << 4) + lh * 8);

    f32x16 acc00 = {0.f}, acc01 = {0.f}, acc10 = {0.f}, acc11 = {0.f};
    acc00 = __builtin_amdgcn_mfma_f32_32x32x16_bf16(a0, b0, acc00, 0, 0, 0);
    acc01 = __builtin_amdgcn_mfma_f32_32x32x16_bf16(a0, b1, acc01, 0, 0, 0);
    acc10 = __builtin_amdgcn_mfma_f32_32x32x16_bf16(a1, b0, acc10, 0, 0, 0);
    acc11 = __builtin_amdgcn_mfma_f32_32x32x16_bf16(a1, b1, acc11, 0, 0, 0);

    int cw = w * 64;  // wave's column base within tile
#pragma unroll
    for (int q = 0; q < 16; ++q) {
        int rf = (q & 3) + 8 * (q >> 2) + 4 * lh;
        ts[rf][cw + lr]           = __fdividef(1.0f, 1.0f + __expf(-acc00[q]));
        ts[rf][cw + 32 + lr]      = __fdividef(1.0f, 1.0f + __expf(-acc01[q]));
        ts[32 + rf][cw + lr]      = __fdividef(1.0f, 1.0f + __expf(-acc10[q]));
        ts[32 + rf][cw + 32 + lr] = __fdividef(1.0f, 1.0f + __expf(-acc11[q]));
    }
    __syncthreads();

    int C0 = bj * 256;
#pragma unroll
    for (int i = 0; i < 16; ++i) {
        int flat = i * 256 + threadIdx.x;
        int row = flat >> 6;           // wave-uniform: i*4 + w
        int c4 = (flat & 63) << 2;     // lane*4
        f32x4 v = *(const f32x4*)&ts[row][c4];
        __builtin_nontemporal_store(v, (f32x4*)&A[(size_t)(R + row) * NN + C0 + c4]);
    }
}

extern "C" void kernel_launch(void* const* d_in, const int* in_sizes, int n_in,
                              void* d_out, int out_size, void* d_ws, size_t ws_size,
                              hipStream_t stream) {
    const float* X  = (const float*)d_in[0];
    const float* W1 = (const float*)d_in[1];
    const float* W2 = (const float*)d_in[2];
    const float* W3 = (const float*)d_in[3];
    const float* ev = (const float*)d_in[4];
    const int*   er = (const int*)d_in[5];
    const int*   ec = (const int*)d_in[6];

    float* A = (float*)d_out;                 // [NN, NN]
    float* Z = A + (size_t)NN * NN;           // [NN, 16]

    // ws layout: [cnt][t1][t2][t3] — cnt+t1 zeroed by ONE memset.
    int*   cnt = (int*)d_ws;                  // [NN]
    float* t1 = (float*)(cnt + NN);           // [NN, 32]  X@W1 (atomic-accum)
    float* t2 = t1 + (size_t)NN * 32;         // [NN, 32]  h1@W2
    float* t3 = t2 + (size_t)NN * 32;         // [NN, 32]  b = spmm(t2)
    unsigned short* Zb = (unsigned short*)t1; // [NN, 16] bf16 (t1 dead by then)

    // ELL edge buffer in the tail of A (decode overwrites it last).
    uint2* ebuf = (uint2*)(A + (size_t)140000000);

    (void)hipMemsetAsync(cnt, 0, NN * sizeof(int) + (size_t)NN * 32 * sizeof(float), stream);

    // gemm1-MFMA (blocks 0..1151) || ELL scatter (blocks 1152..2687)
    k_scatter_gemm1<<<G1B + NE / 256, 256, 0, stream>>>(er, ec, ev, cnt, ebuf, X, W1, t1);

    // t2 = relu(spmm(t1)) @ W2   (one wave per row)
    spmm_gemm32<<<NN * 64 / 256, 256, 0, stream>>>(t1, W2, t2, cnt, ebuf);
    // t3 = b = spmm(t2)          (pure gather)
    spmm32<<<NN * 64 / 256, 256, 0, stream>>>(t2, t3, cnt, ebuf);
    // Z = spmm(relu(b)) @ W3  (+Zb)  — W3 commuted out of the spmm
    spmm_w3<<<NN * 64 / 256, 256, 0, stream>>>(t3, W3, Z, Zb, cnt, ebuf);

    // A = sigmoid(Z @ Z^T) via MFMA, LDS-staged row-major NT flush
    decode_mfma<<<192 * 48, 256, 0, stream>>>(Zb, A);
}

// Round 24
// 198.295 us; speedup vs baseline: 1.0722x; 1.0049x over previous
//
#include <hip/hip_runtime.h>

// GAE: h1 = relu(spmm(X@W1)); h2 = relu(spmm(h1@W2)); Z = spmm(h2@W3);
// A = sigmoid(Z @ Z^T).  Outputs: [A (12288x12288), Z (12288x16)] fp32, concat.
//
// 7 dispatches: memset(cnt) -> [gemm1-MFMA || ELL-scatter] -> reduce_part
//   -> spmm+relu+@W2 -> spmm32 -> spmm+relu+@W3-commuted (+Z,Zb) -> decode_mfma.
// R24 = R23 with the parity race fixed: 12 partials (chunk*2+parity), each
// wave writes a PRIVATE tile; reduce sums 12. Tests atomic-free gemm1 epilogue.

constexpr int NN = 12288;   // nodes
constexpr int NE = 393216;  // edges
constexpr int KD = 1433;    // input dim
constexpr int CAP = 96;     // ELL row capacity (Poisson(32): P(deg>96) ~ 1e-18)

typedef float f32x4 __attribute__((ext_vector_type(4)));
typedef float f32x4u __attribute__((ext_vector_type(4), aligned(4)));  // 4B-aligned vec load
typedef float f32x16 __attribute__((ext_vector_type(16)));
typedef short shortx8 __attribute__((ext_vector_type(8)));

__device__ __forceinline__ unsigned short f2bf(float v) {
    unsigned int b = __float_as_uint(v);
    return (unsigned short)((b + 0x7FFFu + ((b >> 16) & 1u)) >> 16);
}

// ---------------- fused: gemm1 (X@W1 via MFMA, bf16) || ELL scatter ----------------
constexpr int KC = 256;              // k-chunk
constexpr int NCH = 6;               // 256x5 + 153
constexpr int NPART = NCH * 2;       // 12 partials (chunk x parity)
constexpr int XST = KC + 8;          // W^T LDS stride (bf16)
constexpr int G1B = (NN / 64) * NCH; // 192 row-blocks x 6 chunks = 1152

__global__ __launch_bounds__(256) void k_scatter_gemm1(const int* __restrict__ er,
                                                       const int* __restrict__ ec,
                                                       const float* __restrict__ ev,
                                                       int* __restrict__ cnt,
                                                       uint2* __restrict__ ebuf,
                                                       const float* __restrict__ X,
                                                       const float* __restrict__ W,
                                                       float* __restrict__ part) {
    if (blockIdx.x >= G1B) {
        int e = (blockIdx.x - G1B) * 256 + threadIdx.x;
        int r = er[e];
        int p = atomicAdd(&cnt[r], 1);
        if (p < CAP) ebuf[(size_t)r * CAP + p] = make_uint2((unsigned)ec[e], __float_as_uint(ev[e]));
        return;
    }
    __shared__ unsigned short wt[32 * XST];  // W1^T, bf16 [col][k], zero-padded

    int rgB   = blockIdx.x / NCH;        // row block (64 rows)
    int chunk = blockIdx.x % NCH;
    int r0 = rgB * 64;
    int k0 = chunk * KC;
    int kt = min(KC, KD - k0);           // 256 or 153
    int nm = (kt + 15) >> 4;             // 16 or 10
    int t = threadIdx.x;

    // stage W1^T (zero-padded -> zero B kills OOB-k A garbage)
    int wtot = nm * 16 * 32;
    for (int e = t; e < wtot; e += 256) {
        int k = e >> 5, c = e & 31;
        float v = (k < kt) ? W[(size_t)(k0 + k) * 32 + c] : 0.f;
        wt[c * XST + k] = f2bf(v);
    }
    __syncthreads();

    int w = t >> 6, l = t & 63;
    int rg = w >> 1;                     // 32-row group
    int par = w & 1;                     // K-parity
    int lr = l & 31, lh = l >> 5;
    int row = r0 + rg * 32 + lr;
    const float* xr = X + (size_t)row * KD + k0 + lh * 8;
    const unsigned short* wbase = wt + lr * XST + lh * 8;
    f32x16 acc = {0.f};
    for (int m = par; m < nm; m += 2) {
        int kk = m * 16 + lh * 8;        // fragment k start (rel. to k0)
        float xv[8];
        if (kk + 8 <= kt) {
            f32x4u v0 = *(const f32x4u*)(xr + m * 16);
            f32x4u v1 = *(const f32x4u*)(xr + m * 16 + 4);
#pragma unroll
            for (int j = 0; j < 4; ++j) { xv[j] = v0[j]; xv[4 + j] = v1[j]; }
        } else {
#pragma unroll
            for (int j = 0; j < 8; ++j) xv[j] = (kk + j < kt) ? xr[m * 16 + j] : 0.f;
        }
        shortx8 a;
#pragma unroll
        for (int j = 0; j < 8; ++j) a[j] = (short)f2bf(xv[j]);
        shortx8 b = *(const shortx8*)(wbase + m * 16);
        acc = __builtin_amdgcn_mfma_f32_32x32x16_bf16(a, b, acc, 0, 0, 0);
    }
    // D: col=lr, row=(q&3)+8*(q>>2)+4*lh (m74-verified) -> PRIVATE partial
    float* pout = part + ((size_t)(chunk * 2 + par) * NN + r0 + rg * 32) * 32;
#pragma unroll
    for (int q = 0; q < 16; ++q) {
        int rf = (q & 3) + 8 * (q >> 2) + 4 * lh;
        pout[rf * 32 + lr] = acc[q];
    }
}

// ---------------- reduce: t1 = sum over 12 partials ----------------
__global__ __launch_bounds__(256) void reduce_part(const float* __restrict__ part,
                                                   float* __restrict__ t1) {
    int tid = blockIdx.x * 256 + threadIdx.x;   // NN*8 threads, 4 cols each
    size_t off = (size_t)tid * 4;
    f32x4 s = *(const f32x4*)(part + off);
#pragma unroll
    for (int ch = 1; ch < NPART; ++ch)
        s += *(const f32x4*)(part + (size_t)ch * NN * 32 + off);
    *(f32x4*)(t1 + off) = s;
}

// ---------------- layer1: SpMM(ELL) + relu + @W2, edge-split ----------------
__global__ __launch_bounds__(256) void spmm_gemm32(const float* __restrict__ in,
                                                   const float* __restrict__ Wm,
                                                   float* __restrict__ out,
                                                   const int* __restrict__ cnt,
                                                   const uint2* __restrict__ ebuf) {
    int tid = blockIdx.x * 256 + threadIdx.x;
    int r = tid >> 6;               // one wave per row
    int lane = threadIdx.x & 63;
    int c = lane & 31, half = lane >> 5;
    float wcol[32];
#pragma unroll
    for (int k = 0; k < 32; ++k) wcol[k] = Wm[k * 32 + c];
    int deg = min(cnt[r], CAP);
    int mid = (deg >> 1) & ~1;      // even split point (eb4-aligned)
    int lo = half ? mid : 0;
    int hi = half ? deg : mid;
    const uint2* eb2 = ebuf + (size_t)r * CAP;
    const uint4* eb4 = (const uint4*)eb2;
    float acc = 0.f;
    int i = lo;
#pragma unroll 2
    for (; i + 4 <= hi; i += 4) {
        uint4 e01 = eb4[i >> 1], e23 = eb4[(i >> 1) + 1];
        acc += __uint_as_float(e01.y) * in[(size_t)e01.x * 32 + c];
        acc += __uint_as_float(e01.w) * in[(size_t)e01.z * 32 + c];
        acc += __uint_as_float(e23.y) * in[(size_t)e23.x * 32 + c];
        acc += __uint_as_float(e23.w) * in[(size_t)e23.z * 32 + c];
    }
    for (; i < hi; ++i) {
        uint2 e = eb2[i];
        acc += __uint_as_float(e.y) * in[(size_t)e.x * 32 + c];
    }
    float h = fmaxf(acc + __shfl_xor(acc, 32), 0.f);
    float o = 0.f;
#pragma unroll
    for (int k = 0; k < 32; ++k)
        o += __shfl(h, (lane & 32) + k) * wcol[k];
    if (half == 0) out[(size_t)r * 32 + c] = o;
}

// ---------------- layer2: pure SpMM(ELL) width 32, edge-split ----------------
__global__ __launch_bounds__(256) void spmm32(const float* __restrict__ in,
                                              float* __restrict__ out,
                                              const int* __restrict__ cnt,
                                              const uint2* __restrict__ ebuf) {
    int tid = blockIdx.x * 256 + threadIdx.x;
    int r = tid >> 6;
    int lane = threadIdx.x & 63;
    int c = lane & 31, half = lane >> 5;
    int deg = min(cnt[r], CAP);
    int mid = (deg >> 1) & ~1;
    int lo = half ? mid : 0;
    int hi = half ? deg : mid;
    const uint2* eb2 = ebuf + (size_t)r * CAP;
    const uint4* eb4 = (const uint4*)eb2;
    float acc = 0.f;
    int i = lo;
#pragma unroll 2
    for (; i + 4 <= hi; i += 4) {
        uint4 e01 = eb4[i >> 1], e23 = eb4[(i >> 1) + 1];
        acc += __uint_as_float(e01.y) * in[(size_t)e01.x * 32 + c];
        acc += __uint_as_float(e01.w) * in[(size_t)e01.z * 32 + c];
        acc += __uint_as_float(e23.y) * in[(size_t)e23.x * 32 + c];
        acc += __uint_as_float(e23.w) * in[(size_t)e23.z * 32 + c];
    }
    for (; i < hi; ++i) {
        uint2 e = eb2[i];
        acc += __uint_as_float(e.y) * in[(size_t)e.x * 32 + c];
    }
    float s = acc + __shfl_xor(acc, 32);
    if (half == 0) out[(size_t)r * 32 + c] = s;   // pre-relu (relu applied by reader)
}

// ---------------- layer3: Z = (spmm o relu)(b) @ W3  (W3 commuted), edge-split ----------------
__global__ __launch_bounds__(256) void spmm_w3(const float* __restrict__ in,
                                               const float* __restrict__ Wm,
                                               float* __restrict__ Z,
                                               unsigned short* __restrict__ zb,
                                               const int* __restrict__ cnt,
                                               const uint2* __restrict__ ebuf) {
    int tid = blockIdx.x * 256 + threadIdx.x;
    int r = tid >> 6;
    int lane = threadIdx.x & 63;
    int c = lane & 31, half = lane >> 5;
    int co = c & 15;
    float wcol[32];
#pragma unroll
    for (int k = 0; k < 32; ++k) wcol[k] = Wm[k * 16 + co];
    int deg = min(cnt[r], CAP);
    int mid = (deg >> 1) & ~1;
    int lo = half ? mid : 0;
    int hi = half ? deg : mid;
    const uint2* eb2 = ebuf + (size_t)r * CAP;
    const uint4* eb4 = (const uint4*)eb2;
    float acc = 0.f;
    int i = lo;
#pragma unroll 2
    for (; i + 4 <= hi; i += 4) {
        uint4 e01 = eb4[i >> 1], e23 = eb4[(i >> 1) + 1];
        acc += __uint_as_float(e01.y) * fmaxf(in[(size_t)e01.x * 32 + c], 0.f);
        acc += __uint_as_float(e01.w) * fmaxf(in[(size_t)e01.z * 32 + c], 0.f);
        acc += __uint_as_float(e23.y) * fmaxf(in[(size_t)e23.x * 32 + c], 0.f);
        acc += __uint_as_float(e23.w) * fmaxf(in[(size_t)e23.z * 32 + c], 0.f);
    }
    for (; i < hi; ++i) {
        uint2 e = eb2[i];
        acc += __uint_as_float(e.y) * fmaxf(in[(size_t)e.x * 32 + c], 0.f);
    }
    float g = acc + __shfl_xor(acc, 32);   // g[r,c] = spmm(relu(b))[r,c]
    float o = 0.f;
#pragma unroll
    for (int k = 0; k < 32; ++k)
        o += __shfl(g, (lane & 32) + k) * wcol[k];
    if (half == 0 && c < 16) {
        Z[(size_t)r * 16 + co] = o;
        zb[(size_t)r * 16 + co] = f2bf(o);
    }
}

// ---------------- decode via MFMA + LDS-staged row-major flush ----------------
__global__ __launch_bounds__(256) void decode_mfma(const unsigned short* __restrict__ Zb,
                                                   float* __restrict__ A) {
    __shared__ float ts[64][260];
    int id = blockIdx.x;
    int f = (id & 7) * (9216 / 8) + (id >> 3);   // XCD swizzle (bijective: 9216%8==0)
    int bi = f / 48, bj = f % 48;                // 192 x 48 tiles of 64x256
    int w = threadIdx.x >> 6;
    int l = threadIdx.x & 63;
    int R = bi * 64;
    int C = bj * 256 + w * 64;
    int lr = l & 31, lh = l >> 5;

    shortx8 a0 = *(const shortx8*)(Zb + ((size_t)(R + lr) << 4) + lh * 8);
    shortx8 a1 = *(const shortx8*)(Zb + ((size_t)(R + 32 + lr) << 4) + lh * 8);
    shortx8 b0 = *(const shortx8*)(Zb + ((size_t)(C + lr) << 4) + lh * 8);
    shortx8 b1 = *(const shortx8*)(Zb + ((size_t)(C + 32 + lr) << 4) + lh * 8);

    f32x16 acc00 = {0.f}, acc01 = {0.f}, acc10 = {0.f}, acc11 = {0.f};
    acc00 = __builtin_amdgcn_mfma_f32_32x32x16_bf16(a0, b0, acc00, 0, 0, 0);
    acc01 = __builtin_amdgcn_mfma_f32_32x32x16_bf16(a0, b1, acc01, 0, 0, 0);
    acc10 = __builtin_amdgcn_mfma_f32_32x32x16_bf16(a1, b0, acc10, 0, 0, 0);
    acc11 = __builtin_amdgcn_mfma_f32_32x32x16_bf16(a1, b1, acc11, 0, 0, 0);

    int cw = w * 64;  // wave's column base within tile
#pragma unroll
    for (int q = 0; q < 16; ++q) {
        int rf = (q & 3) + 8 * (q >> 2) + 4 * lh;
        ts[rf][cw + lr]           = __fdividef(1.0f, 1.0f + __expf(-acc00[q]));
        ts[rf][cw + 32 + lr]      = __fdividef(1.0f, 1.0f + __expf(-acc01[q]));
        ts[32 + rf][cw + lr]      = __fdividef(1.0f, 1.0f + __expf(-acc10[q]));
        ts[32 + rf][cw + 32 + lr] = __fdividef(1.0f, 1.0f + __expf(-acc11[q]));
    }
    __syncthreads();

    int C0 = bj * 256;
#pragma unroll
    for (int i = 0; i < 16; ++i) {
        int flat = i * 256 + threadIdx.x;
        int row = flat >> 6;           // wave-uniform: i*4 + w
        int c4 = (flat & 63) << 2;     // lane*4
        f32x4 v = *(const f32x4*)&ts[row][c4];
        __builtin_nontemporal_store(v, (f32x4*)&A[(size_t)(R + row) * NN + C0 + c4]);
    }
}

extern "C" void kernel_launch(void* const* d_in, const int* in_sizes, int n_in,
                              void* d_out, int out_size, void* d_ws, size_t ws_size,
                              hipStream_t stream) {
    const float* X  = (const float*)d_in[0];
    const float* W1 = (const float*)d_in[1];
    const float* W2 = (const float*)d_in[2];
    const float* W3 = (const float*)d_in[3];
    const float* ev = (const float*)d_in[4];
    const int*   er = (const int*)d_in[5];
    const int*   ec = (const int*)d_in[6];

    float* A = (float*)d_out;                 // [NN, NN]
    float* Z = A + (size_t)NN * NN;           // [NN, 16]

    // ws layout: [cnt][t1][t2][t3]
    int*   cnt = (int*)d_ws;                  // [NN]
    float* t1 = (float*)(cnt + NN);           // [NN, 32]  X@W1 (reduced)
    float* t2 = t1 + (size_t)NN * 32;         // [NN, 32]  h1@W2
    float* t3 = t2 + (size_t)NN * 32;         // [NN, 32]  b = spmm(t2)
    unsigned short* Zb = (unsigned short*)t1; // [NN, 16] bf16 (t1 dead by then)

    // A-tail scratch (decode overwrites last): ebuf [560MB,569.4MB),
    // part [584MB, 602.9MB). A is 604MB.
    uint2* ebuf = (uint2*)(A + (size_t)140000000);
    float* part = A + (size_t)146000000;      // [NPART][NN][32] = 18.9MB

    (void)hipMemsetAsync(cnt, 0, NN * sizeof(int), stream);

    // gemm1-MFMA (blocks 0..1151) || ELL scatter (blocks 1152..2687)
    k_scatter_gemm1<<<G1B + NE / 256, 256, 0, stream>>>(er, ec, ev, cnt, ebuf, X, W1, part);
    // t1 = sum of 12 partials
    reduce_part<<<NN * 8 / 256, 256, 0, stream>>>(part, t1);

    // t2 = relu(spmm(t1)) @ W2   (one wave per row)
    spmm_gemm32<<<NN * 64 / 256, 256, 0, stream>>>(t1, W2, t2, cnt, ebuf);
    // t3 = b = spmm(t2)          (pure gather)
    spmm32<<<NN * 64 / 256, 256, 0, stream>>>(t2, t3, cnt, ebuf);
    // Z = spmm(relu(b)) @ W3  (+Zb)  — W3 commuted out of the spmm
    spmm_w3<<<NN * 64 / 256, 256, 0, stream>>>(t3, W3, Z, Zb, cnt, ebuf);

    // A = sigmoid(Z @ Z^T) via MFMA, LDS-staged row-major NT flush
    decode_mfma<<<192 * 48, 256, 0, stream>>>(Zb, A);
}